// Round 4
// baseline (730.213 us; speedup 1.0000x reference)
//
#include <hip/hip_runtime.h>
#include <hip/hip_bf16.h>
#include <stdint.h>

#define NL   8192
#define NHI  1024
#define DIMV 2048

typedef __attribute__((ext_vector_type(8))) short short8;
typedef __attribute__((ext_vector_type(4))) float f32x4;

__device__ __forceinline__ unsigned short f2bf(float x){
  unsigned u = __float_as_uint(x);
  u += 0x7FFFu + ((u >> 16) & 1u);
  return (unsigned short)(u >> 16);
}
__device__ __forceinline__ float bf2f(unsigned short b){
  return __uint_as_float(((unsigned)b) << 16);
}
__device__ __forceinline__ unsigned pack2bf(float a, float b){
  return (unsigned)f2bf(a) | ((unsigned)f2bf(b) << 16);
}

__device__ __forceinline__ void gload16(const void* g, void* l){
  __builtin_amdgcn_global_load_lds(
      (const __attribute__((address_space(1))) unsigned int*)g,
      (__attribute__((address_space(3))) unsigned int*)l, 16, 0, 0);
}

// ---------------- row-normalize (and emit bf16 copy) ----------------
template<int WRITE_F32>
__global__ __launch_bounds__(256)
void rownorm_kernel(const float* __restrict__ W, float* __restrict__ outF32,
                    unsigned short* __restrict__ outBf){
  int row = blockIdx.x;
  const float* r = W + (size_t)row * DIMV;
  int base = threadIdx.x * 8;
  float4 x0 = *(const float4*)(r + base);
  float4 x1 = *(const float4*)(r + base + 4);
  float ss = x0.x*x0.x + x0.y*x0.y + x0.z*x0.z + x0.w*x0.w
           + x1.x*x1.x + x1.y*x1.y + x1.z*x1.z + x1.w*x1.w;
  #pragma unroll
  for(int s = 1; s < 64; s <<= 1) ss += __shfl_xor(ss, s, 64);
  __shared__ float red[4];
  if((threadIdx.x & 63) == 0) red[threadIdx.x >> 6] = ss;
  __syncthreads();
  float tot = red[0] + red[1] + red[2] + red[3];
  float inv = 1.0f / sqrtf(tot);
  float y0=x0.x*inv, y1=x0.y*inv, y2=x0.z*inv, y3=x0.w*inv;
  float y4=x1.x*inv, y5=x1.y*inv, y6=x1.z*inv, y7=x1.w*inv;
  if(WRITE_F32){
    float* o = outF32 + (size_t)row * DIMV + base;
    *(float4*)o       = make_float4(y0,y1,y2,y3);
    *(float4*)(o + 4) = make_float4(y4,y5,y6,y7);
  }
  uint4 u;
  u.x = pack2bf(y0,y1); u.y = pack2bf(y2,y3);
  u.z = pack2bf(y4,y5); u.w = pack2bf(y6,y7);
  *(uint4*)(outBf + (size_t)row * DIMV + base) = u;
}

// ---------------- f32 -> bf16 cast ----------------
__global__ __launch_bounds__(256)
void cast_bf16_kernel(const float* __restrict__ in, unsigned short* __restrict__ out){
  size_t i = ((size_t)blockIdx.x * 256 + threadIdx.x) * 8;
  float4 x0 = *(const float4*)(in + i);
  float4 x1 = *(const float4*)(in + i + 4);
  uint4 u;
  u.x = pack2bf(x0.x,x0.y); u.y = pack2bf(x0.z,x0.w);
  u.z = pack2bf(x1.x,x1.y); u.w = pack2bf(x1.z,x1.w);
  *(uint4*)(out + i) = u;
}

// ============== 256x256 8-phase GEMM (T2+T3+T4+T5), NT form ==============
// C[M,N] = scale * A[M,K] x Bt[N,K]^T, bf16 in, 512 threads (8 waves 2Mx4N),
// BK=64, 128 KiB LDS (2 K-tile dbuf). LDS[r][b] = G[r][b ^ ((r&7)<<4)]
// (involution applied on stage SOURCE and on READ; LDS dest linear).
// Stage units per tile (vmcnt order): B0,B1,B2,B3,a0,a2,a1,a3.
// p0 needs first 6 -> vmcnt(2)+barrier at prev p3 / prologue.
// p1 needs a1,a3  -> vmcnt(2)+barrier at p0 (outstanding = 2 old + 2 new).
// Never drains to 0 in steady state (T4).

__device__ __forceinline__ void stageA2(const unsigned short* __restrict__ G, int ldk,
                                        int row0, int kt, int scol, char* dst0,
                                        int tid, int srl){
  gload16(G + (size_t)(row0 + srl)*ldk + kt*64 + scol, dst0 + tid*16);
  gload16(G + (size_t)(row0 + 128 + srl)*ldk + kt*64 + scol, dst0 + 16384 + tid*16);
}
__device__ __forceinline__ void stageB2(const unsigned short* __restrict__ G, int ldk,
                                        int row0, int kt, int scol, char* dst0,
                                        int tid, int srl){
  gload16(G + (size_t)(row0 + srl)*ldk + kt*64 + scol, dst0 + tid*16);
  gload16(G + (size_t)(row0 + 64 + srl)*ldk + kt*64 + scol, dst0 + 8192 + tid*16);
}

// phase: ds_read(buffer d) || stage(buffer d^1) ; [vmcnt] ; barrier ;
//        lgkmcnt(0) ; setprio(1) 16xMFMA setprio(0) ; barrier
#define PHASE(MH, CB, PRE) { \
  short8 a0_ = *(const short8*)(pa + ((MH)*64 +  0 + rA)*128 + (CB)); \
  short8 a1_ = *(const short8*)(pa + ((MH)*64 + 16 + rA)*128 + (CB)); \
  short8 a2_ = *(const short8*)(pa + ((MH)*64 + 32 + rA)*128 + (CB)); \
  short8 a3_ = *(const short8*)(pa + ((MH)*64 + 48 + rA)*128 + (CB)); \
  short8 b0_ = *(const short8*)(pb + (rB0 +  0)*128 + (CB)); \
  short8 b1_ = *(const short8*)(pb + (rB0 + 16)*128 + (CB)); \
  short8 b2_ = *(const short8*)(pb + (rB0 + 32)*128 + (CB)); \
  short8 b3_ = *(const short8*)(pb + (rB0 + 48)*128 + (CB)); \
  PRE; \
  __builtin_amdgcn_s_barrier(); \
  asm volatile("s_waitcnt lgkmcnt(0)" ::: "memory"); \
  __builtin_amdgcn_sched_barrier(0); \
  __builtin_amdgcn_s_setprio(1); \
  acc[(MH)*4+0][0] = __builtin_amdgcn_mfma_f32_16x16x32_bf16(a0_, b0_, acc[(MH)*4+0][0],0,0,0); \
  acc[(MH)*4+0][1] = __builtin_amdgcn_mfma_f32_16x16x32_bf16(a0_, b1_, acc[(MH)*4+0][1],0,0,0); \
  acc[(MH)*4+0][2] = __builtin_amdgcn_mfma_f32_16x16x32_bf16(a0_, b2_, acc[(MH)*4+0][2],0,0,0); \
  acc[(MH)*4+0][3] = __builtin_amdgcn_mfma_f32_16x16x32_bf16(a0_, b3_, acc[(MH)*4+0][3],0,0,0); \
  acc[(MH)*4+1][0] = __builtin_amdgcn_mfma_f32_16x16x32_bf16(a1_, b0_, acc[(MH)*4+1][0],0,0,0); \
  acc[(MH)*4+1][1] = __builtin_amdgcn_mfma_f32_16x16x32_bf16(a1_, b1_, acc[(MH)*4+1][1],0,0,0); \
  acc[(MH)*4+1][2] = __builtin_amdgcn_mfma_f32_16x16x32_bf16(a1_, b2_, acc[(MH)*4+1][2],0,0,0); \
  acc[(MH)*4+1][3] = __builtin_amdgcn_mfma_f32_16x16x32_bf16(a1_, b3_, acc[(MH)*4+1][3],0,0,0); \
  acc[(MH)*4+2][0] = __builtin_amdgcn_mfma_f32_16x16x32_bf16(a2_, b0_, acc[(MH)*4+2][0],0,0,0); \
  acc[(MH)*4+2][1] = __builtin_amdgcn_mfma_f32_16x16x32_bf16(a2_, b1_, acc[(MH)*4+2][1],0,0,0); \
  acc[(MH)*4+2][2] = __builtin_amdgcn_mfma_f32_16x16x32_bf16(a2_, b2_, acc[(MH)*4+2][2],0,0,0); \
  acc[(MH)*4+2][3] = __builtin_amdgcn_mfma_f32_16x16x32_bf16(a2_, b3_, acc[(MH)*4+2][3],0,0,0); \
  acc[(MH)*4+3][0] = __builtin_amdgcn_mfma_f32_16x16x32_bf16(a3_, b0_, acc[(MH)*4+3][0],0,0,0); \
  acc[(MH)*4+3][1] = __builtin_amdgcn_mfma_f32_16x16x32_bf16(a3_, b1_, acc[(MH)*4+3][1],0,0,0); \
  acc[(MH)*4+3][2] = __builtin_amdgcn_mfma_f32_16x16x32_bf16(a3_, b2_, acc[(MH)*4+3][2],0,0,0); \
  acc[(MH)*4+3][3] = __builtin_amdgcn_mfma_f32_16x16x32_bf16(a3_, b3_, acc[(MH)*4+3][3],0,0,0); \
  __builtin_amdgcn_s_setprio(0); \
  __builtin_amdgcn_s_barrier(); \
}

template<int OUT_BF16, int MIRROR>
__global__ __launch_bounds__(512, 2)
void gemm256_kernel(const unsigned short* __restrict__ A,
                    const unsigned short* __restrict__ Bt,
                    float* __restrict__ Cf, unsigned short* __restrict__ Cb,
                    int M, int N, int K, float scale){
  __shared__ __align__(16) char smem[131072];
  int tid = threadIdx.x, lane = tid & 63, wid = tid >> 6;
  int wm = wid >> 2, wn = wid & 3;

  int mBase, nBase;
  if(MIRROR){
    int nwg = gridDim.x;                     // 528 = 8*66
    int id = blockIdx.x;
    int cpx = nwg >> 3;
    id = (id & 7) * cpx + (id >> 3);
    int bi = 0;
    while(((bi+1)*32 - (((bi+1)*bi) >> 1)) <= id) bi++;
    int off = bi*32 - ((bi*(bi-1)) >> 1);
    int bj = bi + (id - off);
    mBase = bi * 256; nBase = bj * 256;
  } else {
    int gx = gridDim.x;
    int nwg = gx * gridDim.y;
    int id = blockIdx.y * gx + blockIdx.x;
    if((nwg & 7) == 0){ int cpx = nwg >> 3; id = (id & 7) * cpx + (id >> 3); }
    mBase = (id / gx) * 256; nBase = (id % gx) * 256;
  }

  f32x4 acc[8][4];
  #pragma unroll
  for(int i=0;i<8;i++)
    #pragma unroll
    for(int j=0;j<4;j++) acc[i][j] = (f32x4){0.f,0.f,0.f,0.f};

  // stage-side addressing (inverse swizzle on global source; LDS dest linear)
  int srl  = tid >> 3;                                    // row within 64-row unit
  int scol = (((tid & 7) * 16) ^ ((srl & 7) << 4)) >> 1;  // source col element
  // read-side addressing
  int rA  = lane & 15;
  int rB0 = (wn & 1) * 64 + rA;
  int cbK0 = (((lane >> 4) * 16)      ^ ((lane & 7) << 4));
  int cbK1 = ((64 + (lane >> 4) * 16) ^ ((lane & 7) << 4));

  int nT = K >> 6;
  // prologue: stage K-tile 0 into dbuf 0; confirm first 6 units for p0
  stageB2(Bt, K, nBase,       0, scol, smem + 65536,         tid, srl);
  stageB2(Bt, K, nBase + 128, 0, scol, smem + 65536 + 16384, tid, srl);
  stageA2(A,  K, mBase,       0, scol, smem,                 tid, srl);  // a0,a2
  stageA2(A,  K, mBase + 64,  0, scol, smem + 8192,          tid, srl);  // a1,a3
  asm volatile("s_waitcnt vmcnt(2)" ::: "memory");
  __builtin_amdgcn_s_barrier();

  for(int t = 0; t < nT; ++t){
    int d = t & 1, d1 = d ^ 1, k1 = t + 1;
    bool st = (k1 < nT);
    const char* pa = smem + d*32768 + wm*16384;
    const char* pb = smem + 65536 + d*32768 + (wn>>1)*16384;
    // p0 (MH=0,ks=0): stage B0',B1'; confirm a1,a3 of tile t
    PHASE(0, cbK0,
      if(st){ stageB2(Bt, K, nBase, k1, scol, smem + 65536 + d1*32768, tid, srl);
              asm volatile("s_waitcnt vmcnt(2)" ::: "memory"); }
      else  { asm volatile("s_waitcnt vmcnt(0)" ::: "memory"); } )
    // p1 (MH=1,ks=0): stage B2',B3'
    PHASE(1, cbK0,
      if(st) stageB2(Bt, K, nBase + 128, k1, scol, smem + 65536 + d1*32768 + 16384, tid, srl); )
    // p2 (MH=0,ks=1): stage a0',a2'
    PHASE(0, cbK1,
      if(st) stageA2(A, K, mBase, k1, scol, smem + d1*32768, tid, srl); )
    // p3 (MH=1,ks=1): stage a1',a3'; confirm first 6 units of tile t+1
    PHASE(1, cbK1,
      if(st){ stageA2(A, K, mBase + 64, k1, scol, smem + d1*32768 + 8192, tid, srl);
              asm volatile("s_waitcnt vmcnt(2)" ::: "memory"); } )
  }

  // direct C-write
  int crow0 = mBase + wm*128 + (lane>>4)*4;
  int ccol0 = nBase + wn*64 + (lane&15);
  #pragma unroll
  for(int i=0;i<8;i++)
    #pragma unroll
    for(int j=0;j<4;j++)
      #pragma unroll
      for(int r=0;r<4;r++){
        float v = acc[i][j][r] * scale;
        size_t off = (size_t)(crow0 + i*16 + r) * N + ccol0 + j*16;
        if(OUT_BF16) Cb[off] = f2bf(v);
        else         Cf[off] = v;
      }

  // mirrored transposed tile for symmetric output (wave-local LDS transpose)
  if(MIRROR && mBase != nBase){
    float* T = (float*)(void*)(smem + wid * 8448);   // 64 x 33 f32 per wave
    int ln15 = lane & 15, lh = lane >> 4;
    #pragma unroll
    for(int c2 = 0; c2 < 4; c2++){
      #pragma unroll
      for(int ii = 0; ii < 2; ii++)
        #pragma unroll
        for(int j = 0; j < 4; j++)
          #pragma unroll
          for(int r = 0; r < 4; r++)
            T[(j*16 + ln15)*33 + ii*16 + lh*4 + r] = acc[c2*2+ii][j][r] * scale;
      asm volatile("s_waitcnt lgkmcnt(0)" ::: "memory");
      __builtin_amdgcn_sched_barrier(0);
      size_t gb = (size_t)(nBase + wn*64 + lane) * N + (mBase + wm*128 + c2*32);
      #pragma unroll
      for(int k4 = 0; k4 < 8; k4++){
        float4 v;
        v.x = T[lane*33 + k4*4 + 0];
        v.y = T[lane*33 + k4*4 + 1];
        v.z = T[lane*33 + k4*4 + 2];
        v.w = T[lane*33 + k4*4 + 3];
        *(float4*)(Cf + gb + k4*4) = v;
      }
      asm volatile("s_waitcnt lgkmcnt(0)" ::: "memory");
      __builtin_amdgcn_sched_barrier(0);
    }
  }
}

// ---------------- m97-style 128x128 NT GEMM (small shapes / split-K) ----------------
template<int OUT_BF16>
__global__ __launch_bounds__(256, 2)
void gemm_bt_kernel(const unsigned short* __restrict__ A,
                    const unsigned short* __restrict__ Bt,
                    float* __restrict__ Cf, unsigned short* __restrict__ Cb,
                    int M, int N, int K, float scale){
  __shared__ __align__(16) char smem[32768];
  unsigned short* sA = (unsigned short*)smem;
  unsigned short* sB = sA + 128 * 64;

  int tid = threadIdx.x, lane = tid & 63, wid = tid >> 6;
  int gx = gridDim.x, gy = gridDim.y;
  int nwg = gx * gy;
  int id = blockIdx.y * gx + blockIdx.x;
  if((nwg & 7) == 0){ int cpx = nwg >> 3; id = (id & 7) * cpx + (id >> 3); }
  int mBase = (id / gx) * 128, nBase = (id % gx) * 128;

  int chRow = lane >> 3;
  int chCol = (lane & 7) * 8;
  int wm = wid >> 1, wn = wid & 1;

  f32x4 acc[4][4];
  #pragma unroll
  for(int i=0;i<4;i++)
    #pragma unroll
    for(int j=0;j<4;j++) acc[i][j] = (f32x4){0.f,0.f,0.f,0.f};

  int kChunk = K / (int)gridDim.z;
  int kStart = kChunk * (int)blockIdx.z;
  if(!OUT_BF16) Cf += (size_t)blockIdx.z * M * N;

  for(int k0 = kStart; k0 < kStart + kChunk; k0 += 64){
    #pragma unroll
    for(int i = 0; i < 4; i++){
      int ch = wid * 4 + i;
      int arow = ch * 8 + chRow;
      gload16(A  + (size_t)(mBase + arow) * K + k0 + chCol, &sA[ch * 512]);
      gload16(Bt + (size_t)(nBase + arow) * K + k0 + chCol, &sB[ch * 512]);
    }
    __syncthreads();
    #pragma unroll
    for(int kk = 0; kk < 64; kk += 32){
      short8 a[4], b[4];
      int krd = kk + (lane >> 4) * 8;
      #pragma unroll
      for(int i = 0; i < 4; i++){
        int row = wm * 64 + i * 16 + (lane & 15);
        a[i] = *reinterpret_cast<const short8*>(&sA[row * 64 + krd]);
        int col = wn * 64 + i * 16 + (lane & 15);
        b[i] = *reinterpret_cast<const short8*>(&sB[col * 64 + krd]);
      }
      #pragma unroll
      for(int i = 0; i < 4; i++)
        #pragma unroll
        for(int j = 0; j < 4; j++)
          acc[i][j] = __builtin_amdgcn_mfma_f32_16x16x32_bf16(a[i], b[j], acc[i][j], 0, 0, 0);
    }
    __syncthreads();
  }

  #pragma unroll
  for(int i = 0; i < 4; i++){
    #pragma unroll
    for(int j = 0; j < 4; j++){
      int row = mBase + wm * 64 + i * 16 + (lane >> 4) * 4;
      int col = nBase + wn * 64 + j * 16 + (lane & 15);
      #pragma unroll
      for(int r = 0; r < 4; r++){
        float v = acc[i][j][r] * scale;
        size_t off = (size_t)(row + r) * N + col;
        if(OUT_BF16) Cb[off] = f2bf(v);
        else         Cf[off] = v;
      }
    }
  }
}

// ---------------- sparsemax: one wave per row of 1024 ----------------
__global__ __launch_bounds__(256)
void sparsemax_kernel(float* __restrict__ S, unsigned short* __restrict__ attnBf){
  int wid = threadIdx.x >> 6, lane = threadIdx.x & 63;
  int row = blockIdx.x * 4 + wid;
  float* z = S + (size_t)row * NHI;
  float v[16];
  #pragma unroll
  for(int j = 0; j < 16; j++) v[j] = z[j * 64 + lane];
  float mx = v[0];
  #pragma unroll
  for(int j = 1; j < 16; j++) mx = fmaxf(mx, v[j]);
  #pragma unroll
  for(int s = 1; s < 64; s <<= 1) mx = fmaxf(mx, __shfl_xor(mx, s, 64));
  float lo = mx - 1.0f, hi = mx;
  for(int it = 0; it < 40; it++){
    float mid = 0.5f * (lo + hi);
    float sum = 0.f;
    #pragma unroll
    for(int j = 0; j < 16; j++) sum += fmaxf(v[j] - mid, 0.f);
    #pragma unroll
    for(int s = 1; s < 64; s <<= 1) sum += __shfl_xor(sum, s, 64);
    if(sum >= 1.0f) lo = mid; else hi = mid;
  }
  float cnt = 0.f, ssum = 0.f;
  #pragma unroll
  for(int j = 0; j < 16; j++){
    if(v[j] > lo){ cnt += 1.f; ssum += v[j]; }
  }
  #pragma unroll
  for(int s = 1; s < 64; s <<= 1){
    cnt  += __shfl_xor(cnt,  s, 64);
    ssum += __shfl_xor(ssum, s, 64);
  }
  float tau = (ssum - 1.0f) / cnt;
  #pragma unroll
  for(int j = 0; j < 16; j++){
    float a = fmaxf(v[j] - tau, 0.f);
    z[j * 64 + lane] = a;
    attnBf[(size_t)row * NHI + j * 64 + lane] = f2bf(a);
  }
}

// ---------------- column sums of attn (f32, [8192,1024]) ----------------
__global__ __launch_bounds__(256)
void colsum_part_kernel(const float* __restrict__ attn, float* __restrict__ part){
  int chunk = blockIdx.x;  // 256 chunks x 32 rows
  int t = threadIdx.x;
  const float* p = attn + (size_t)chunk * 32 * NHI;
  float a0=0,a1=0,a2=0,a3=0;
  for(int r = 0; r < 32; r++){
    a0 += p[(size_t)r*NHI + t];
    a1 += p[(size_t)r*NHI + t + 256];
    a2 += p[(size_t)r*NHI + t + 512];
    a3 += p[(size_t)r*NHI + t + 768];
  }
  float* q = part + (size_t)chunk * NHI;
  q[t]=a0; q[t+256]=a1; q[t+512]=a2; q[t+768]=a3;
}
__global__ __launch_bounds__(256)
void colsum_final_kernel(const float* __restrict__ part, float* __restrict__ colsum){
  int c = blockIdx.x * 256 + threadIdx.x;
  float s = 0.f;
  for(int i = 0; i < 256; i++) s += part[(size_t)i * NHI + c];
  colsum[c] = s;
}

// ---------------- bf16 transpose: in[R,C] -> out[C,R] ----------------
__global__ __launch_bounds__(256)
void transpose_bf16_kernel(const unsigned short* __restrict__ in,
                           unsigned short* __restrict__ out, int R, int C){
  __shared__ unsigned short tile[64][65];
  int c0 = blockIdx.x * 64, r0 = blockIdx.y * 64;
  int t = threadIdx.x;
  int ci = t & 63, r4 = t >> 6;
  #pragma unroll
  for(int k = 0; k < 16; k++){
    int r = k * 4 + r4;
    tile[r][ci] = in[(size_t)(r0 + r) * C + c0 + ci];
  }
  __syncthreads();
  #pragma unroll
  for(int k = 0; k < 16; k++){
    int cc = k * 4 + r4;
    out[(size_t)(c0 + cc) * R + r0 + ci] = tile[ci][cc];
  }
}

// ------ Mt[d,h] = highNT[d,h] + (sum_z aggP_z[d,h]) / (colsum[h]+eps) ------
__global__ __launch_bounds__(256)
void mt_kernel(const unsigned short* __restrict__ highNT, const float* __restrict__ aggP,
               const float* __restrict__ colsum, unsigned short* __restrict__ Mt){
  int idx = blockIdx.x * 256 + threadIdx.x;      // 2048*1024
  int h = idx & 1023;
  float s = aggP[idx] + aggP[idx + 2097152] + aggP[idx + 4194304] + aggP[idx + 6291456];
  float val = bf2f(highNT[idx]) + s / (colsum[h] + 1e-10f);
  Mt[idx] = f2bf(val);
}

extern "C" void kernel_launch(void* const* d_in, const int* in_sizes, int n_in,
                              void* d_out, int out_size, void* d_ws, size_t ws_size,
                              hipStream_t stream){
  const float* low_w  = (const float*)d_in[0];
  const float* high_w = (const float*)d_in[1];
  const float* Wq     = (const float*)d_in[2];
  const float* Wk     = (const float*)d_in[3];
  float* out = (float*)d_out;

  char* ws = (char*)d_ws;
  unsigned short* lowN  = (unsigned short*)(ws);                 // 32 MB; dead after lowNT
  float*          aggP  = (float*)(ws);                          // reuses lowN: 4x8MB partials
  unsigned short* highN = (unsigned short*)(ws + 33554432);      //  4 MB
  unsigned short* WqB   = (unsigned short*)(ws + 37748736);      //  8 MB
  unsigned short* WkB   = (unsigned short*)(ws + 46137344);      //  8 MB
  unsigned short* attnB = (unsigned short*)(ws + 37748736);      // reuse Wq/Wk (16 MB)
  unsigned short* qB    = (unsigned short*)(ws + 54525952);      // 32 MB
  unsigned short* lowNT = qB;                                    // reuse after scores
  unsigned short* kB    = (unsigned short*)(ws + 88080384);      //  4 MB; dead after scores
  float*          part  = (float*)(ws + 88080384);               // reuse kB: 1 MB
  float*          colsum= (float*)(ws + 88080384 + 1048576);     //  4 KB
  unsigned short* attnT = (unsigned short*)(ws + 92274688);      // 16 MB
  unsigned short* Mt    = (unsigned short*)(ws + 109051904);     //  4 MB
  unsigned short* highNT= (unsigned short*)(ws + 113246208);     //  4 MB

  float* out_lowc    = out;               // [8192,2048]
  float* out_lowcos  = out + 16777216;    // [8192,8192]
  float* out_high    = out + 83886080;    // [8192,2048]
  float* out_highcos = out + 100663296;   // [1024,1024]
  float* out_attn    = out + 101711872;   // [8192,1024]

  const float scl = 1.0f / sqrtf((float)DIMV);

  // 1. normalize rows
  rownorm_kernel<1><<<NL,  256, 0, stream>>>(low_w,  out_lowc, lowN);
  rownorm_kernel<0><<<NHI, 256, 0, stream>>>(high_w, nullptr,  highN);
  // 2. cast weights
  cast_bf16_kernel<<<2048, 256, 0, stream>>>(Wq, WqB);
  cast_bf16_kernel<<<2048, 256, 0, stream>>>(Wk, WkB);
  // 3. low_cos = lowN lowN^T [8192,8192], symmetric upper triangle + mirror (8-phase)
  gemm256_kernel<0,1><<<528, 512, 0, stream>>>(lowN, lowN, out_lowcos, nullptr,
                                               NL, NL, DIMV, 1.0f);
  // 4. high_cos = highN highN^T [1024,1024] (m97 kernel)
  gemm_bt_kernel<0><<<dim3(8,8), 256, 0, stream>>>(highN, highN, out_highcos, nullptr,
                                                   NHI, NHI, DIMV, 1.0f);
  // 5. q = lowN Wq^T (bf16, 8-phase)   k = highN Wk^T (bf16, m97)
  gemm256_kernel<1,0><<<dim3(8,32), 512, 0, stream>>>(lowN, WqB, nullptr, qB,
                                                      NL, DIMV, DIMV, 1.0f);
  gemm_bt_kernel<1><<<dim3(16,8), 256, 0, stream>>>(highN, WkB, nullptr, kB,
                                                    NHI, DIMV, DIMV, 1.0f);
  // 6. scores = scale * q k^T -> f32 (8-phase)
  gemm256_kernel<0,0><<<dim3(4,32), 512, 0, stream>>>(qB, kB, out_attn, nullptr,
                                                      NL, NHI, DIMV, scl);
  // 7. sparsemax rows in-place (+ bf16 copy into reused Wq/Wk space)
  sparsemax_kernel<<<NL/4, 256, 0, stream>>>(out_attn, attnB);
  // 8. column sums of attn (part reuses dead kB)
  colsum_part_kernel<<<256, 256, 0, stream>>>(out_attn, part);
  colsum_final_kernel<<<4, 256, 0, stream>>>(part, colsum);
  // 9. transposes: attnT [1024,8192], lowNT [2048,8192], highNT [2048,1024]
  transpose_bf16_kernel<<<dim3(NHI/64, NL/64), 256, 0, stream>>>(attnB, attnT, NL, NHI);
  transpose_bf16_kernel<<<dim3(DIMV/64, NL/64), 256, 0, stream>>>(lowN, lowNT, NL, DIMV);
  transpose_bf16_kernel<<<dim3(DIMV/64, NHI/64), 256, 0, stream>>>(highN, highNT, NHI, DIMV);
  // 10. aggP_z[d,h] = sum_{k in chunk z} lowN[k,d] attn[k,h]  (m97 split-K x4)
  gemm_bt_kernel<0><<<dim3(8,16,4), 256, 0, stream>>>(lowNT, attnT, aggP, nullptr,
                                                      DIMV, NHI, NL, 1.0f);
  // 11. Mt = highN^T + sum(aggP) / colsum  (bf16, [2048,1024])
  mt_kernel<<<8192, 256, 0, stream>>>(highNT, aggP, colsum, Mt);
  // 12. output_high = attn (highN + agg) = attn Mt^T  [8192,2048] (8-phase)
  gemm256_kernel<0,0><<<dim3(8,32), 512, 0, stream>>>(attnB, Mt, out_high, nullptr,
                                                      NL, DIMV, NHI, 1.0f);
}

// Round 5
// 716.919 us; speedup vs baseline: 1.0185x; 1.0185x over previous
//
#include <hip/hip_runtime.h>
#include <hip/hip_bf16.h>
#include <stdint.h>

#define NL   8192
#define NHI  1024
#define DIMV 2048

typedef __attribute__((ext_vector_type(8))) short short8;
typedef __attribute__((ext_vector_type(4))) float f32x4;

__device__ __forceinline__ unsigned short f2bf(float x){
  unsigned u = __float_as_uint(x);
  u += 0x7FFFu + ((u >> 16) & 1u);
  return (unsigned short)(u >> 16);
}
__device__ __forceinline__ float bf2f(unsigned short b){
  return __uint_as_float(((unsigned)b) << 16);
}
__device__ __forceinline__ unsigned pack2bf(float a, float b){
  return (unsigned)f2bf(a) | ((unsigned)f2bf(b) << 16);
}

__device__ __forceinline__ void gload16(const void* g, void* l){
  __builtin_amdgcn_global_load_lds(
      (const __attribute__((address_space(1))) unsigned int*)g,
      (__attribute__((address_space(3))) unsigned int*)l, 16, 0, 0);
}

// ---------------- row-normalize (and emit bf16 copy) ----------------
template<int WRITE_F32>
__global__ __launch_bounds__(256)
void rownorm_kernel(const float* __restrict__ W, float* __restrict__ outF32,
                    unsigned short* __restrict__ outBf){
  int row = blockIdx.x;
  const float* r = W + (size_t)row * DIMV;
  int base = threadIdx.x * 8;
  float4 x0 = *(const float4*)(r + base);
  float4 x1 = *(const float4*)(r + base + 4);
  float ss = x0.x*x0.x + x0.y*x0.y + x0.z*x0.z + x0.w*x0.w
           + x1.x*x1.x + x1.y*x1.y + x1.z*x1.z + x1.w*x1.w;
  #pragma unroll
  for(int s = 1; s < 64; s <<= 1) ss += __shfl_xor(ss, s, 64);
  __shared__ float red[4];
  if((threadIdx.x & 63) == 0) red[threadIdx.x >> 6] = ss;
  __syncthreads();
  float tot = red[0] + red[1] + red[2] + red[3];
  float inv = 1.0f / sqrtf(tot);
  float y0=x0.x*inv, y1=x0.y*inv, y2=x0.z*inv, y3=x0.w*inv;
  float y4=x1.x*inv, y5=x1.y*inv, y6=x1.z*inv, y7=x1.w*inv;
  if(WRITE_F32){
    float* o = outF32 + (size_t)row * DIMV + base;
    *(float4*)o       = make_float4(y0,y1,y2,y3);
    *(float4*)(o + 4) = make_float4(y4,y5,y6,y7);
  }
  uint4 u;
  u.x = pack2bf(y0,y1); u.y = pack2bf(y2,y3);
  u.z = pack2bf(y4,y5); u.w = pack2bf(y6,y7);
  *(uint4*)(outBf + (size_t)row * DIMV + base) = u;
}

// ---------------- f32 -> bf16 cast ----------------
__global__ __launch_bounds__(256)
void cast_bf16_kernel(const float* __restrict__ in, unsigned short* __restrict__ out){
  size_t i = ((size_t)blockIdx.x * 256 + threadIdx.x) * 8;
  float4 x0 = *(const float4*)(in + i);
  float4 x1 = *(const float4*)(in + i + 4);
  uint4 u;
  u.x = pack2bf(x0.x,x0.y); u.y = pack2bf(x0.z,x0.w);
  u.z = pack2bf(x1.x,x1.y); u.w = pack2bf(x1.z,x1.w);
  *(uint4*)(out + i) = u;
}

// ============== 256x256 8-phase GEMM (T2+T3+T4+T5), NT form ==============
// C[M,N] = scale * A[M,K] x Bt[N,K]^T, bf16 in, 512 threads (8 waves 2Mx4N),
// BK=64, 128 KiB LDS (2 K-tile dbuf). LDS[r][b] = G[r][b ^ ((r&7)<<4)].
// ds_reads pipelined ONE PHASE AHEAD (issued after B1, consumed next phase;
// compiler emits counted lgkmcnt(8) before the MFMA cluster). B-fragments
// held across phase pairs (read at prologue/p1/p3 only): 24KB LDS/wave/tile.
// Stage units per tile (vmcnt order): v_a,v_b,v_c,v_d (B), u_a,u_c, u_b,u_d (A).
// Confirms: p0 vmcnt(2)+B1 -> u_b,u_d readable; p3 vmcnt(2)+B1 -> first 6 of
// next tile readable. Never drains to 0 in steady state (T4).

__device__ __forceinline__ void stageA2(const unsigned short* __restrict__ G, int ldk,
                                        int row0, int kt, int scol, char* dst0,
                                        int tid, int srl){
  gload16(G + (size_t)(row0 + srl)*ldk + kt*64 + scol, dst0 + tid*16);
  gload16(G + (size_t)(row0 + 128 + srl)*ldk + kt*64 + scol, dst0 + 16384 + tid*16);
}
__device__ __forceinline__ void stageB2(const unsigned short* __restrict__ G, int ldk,
                                        int row0, int kt, int scol, char* dst0,
                                        int tid, int srl){
  gload16(G + (size_t)(row0 + srl)*ldk + kt*64 + scol, dst0 + tid*16);
  gload16(G + (size_t)(row0 + 64 + srl)*ldk + kt*64 + scol, dst0 + 8192 + tid*16);
}

#define READA(P, PTR, MHOFF, CB) \
  P##0 = *(const short8*)((PTR) + ((MHOFF) +  0 + rA)*128 + (CB)); \
  P##1 = *(const short8*)((PTR) + ((MHOFF) + 16 + rA)*128 + (CB)); \
  P##2 = *(const short8*)((PTR) + ((MHOFF) + 32 + rA)*128 + (CB)); \
  P##3 = *(const short8*)((PTR) + ((MHOFF) + 48 + rA)*128 + (CB));

#define READB(P, PTR, CB) \
  P##0 = *(const short8*)((PTR) + (rB0 +  0)*128 + (CB)); \
  P##1 = *(const short8*)((PTR) + (rB0 + 16)*128 + (CB)); \
  P##2 = *(const short8*)((PTR) + (rB0 + 32)*128 + (CB)); \
  P##3 = *(const short8*)((PTR) + (rB0 + 48)*128 + (CB));

#define MFMA16(AP, BP, R) \
  __builtin_amdgcn_s_setprio(1); \
  acc[(R)+0][0] = __builtin_amdgcn_mfma_f32_16x16x32_bf16(AP##0, BP##0, acc[(R)+0][0],0,0,0); \
  acc[(R)+0][1] = __builtin_amdgcn_mfma_f32_16x16x32_bf16(AP##0, BP##1, acc[(R)+0][1],0,0,0); \
  acc[(R)+0][2] = __builtin_amdgcn_mfma_f32_16x16x32_bf16(AP##0, BP##2, acc[(R)+0][2],0,0,0); \
  acc[(R)+0][3] = __builtin_amdgcn_mfma_f32_16x16x32_bf16(AP##0, BP##3, acc[(R)+0][3],0,0,0); \
  acc[(R)+1][0] = __builtin_amdgcn_mfma_f32_16x16x32_bf16(AP##1, BP##0, acc[(R)+1][0],0,0,0); \
  acc[(R)+1][1] = __builtin_amdgcn_mfma_f32_16x16x32_bf16(AP##1, BP##1, acc[(R)+1][1],0,0,0); \
  acc[(R)+1][2] = __builtin_amdgcn_mfma_f32_16x16x32_bf16(AP##1, BP##2, acc[(R)+1][2],0,0,0); \
  acc[(R)+1][3] = __builtin_amdgcn_mfma_f32_16x16x32_bf16(AP##1, BP##3, acc[(R)+1][3],0,0,0); \
  acc[(R)+2][0] = __builtin_amdgcn_mfma_f32_16x16x32_bf16(AP##2, BP##0, acc[(R)+2][0],0,0,0); \
  acc[(R)+2][1] = __builtin_amdgcn_mfma_f32_16x16x32_bf16(AP##2, BP##1, acc[(R)+2][1],0,0,0); \
  acc[(R)+2][2] = __builtin_amdgcn_mfma_f32_16x16x32_bf16(AP##2, BP##2, acc[(R)+2][2],0,0,0); \
  acc[(R)+2][3] = __builtin_amdgcn_mfma_f32_16x16x32_bf16(AP##2, BP##3, acc[(R)+2][3],0,0,0); \
  acc[(R)+3][0] = __builtin_amdgcn_mfma_f32_16x16x32_bf16(AP##3, BP##0, acc[(R)+3][0],0,0,0); \
  acc[(R)+3][1] = __builtin_amdgcn_mfma_f32_16x16x32_bf16(AP##3, BP##1, acc[(R)+3][1],0,0,0); \
  acc[(R)+3][2] = __builtin_amdgcn_mfma_f32_16x16x32_bf16(AP##3, BP##2, acc[(R)+3][2],0,0,0); \
  acc[(R)+3][3] = __builtin_amdgcn_mfma_f32_16x16x32_bf16(AP##3, BP##3, acc[(R)+3][3],0,0,0); \
  __builtin_amdgcn_s_setprio(0);

template<int OUT_BF16, int MIRROR>
__global__ __launch_bounds__(512, 2)
void gemm256_kernel(const unsigned short* __restrict__ A,
                    const unsigned short* __restrict__ Bt,
                    float* __restrict__ Cf, unsigned short* __restrict__ Cb,
                    int M, int N, int K, float scale){
  __shared__ __align__(16) char smem[131072];
  int tid = threadIdx.x, lane = tid & 63, wid = tid >> 6;
  int wm = wid >> 2, wn = wid & 3;

  int mBase, nBase;
  if(MIRROR){
    int nwg = gridDim.x;                     // 528 = 8*66
    int id = blockIdx.x;
    int cpx = nwg >> 3;
    id = (id & 7) * cpx + (id >> 3);
    int bi = 0;
    while(((bi+1)*32 - (((bi+1)*bi) >> 1)) <= id) bi++;
    int off = bi*32 - ((bi*(bi-1)) >> 1);
    int bj = bi + (id - off);
    mBase = bi * 256; nBase = bj * 256;
  } else {
    int gx = gridDim.x;
    int nwg = gx * gridDim.y;
    int id = blockIdx.y * gx + blockIdx.x;
    if((nwg & 7) == 0){ int cpx = nwg >> 3; id = (id & 7) * cpx + (id >> 3); }
    mBase = (id / gx) * 256; nBase = (id % gx) * 256;
  }

  f32x4 acc[8][4];
  #pragma unroll
  for(int i=0;i<8;i++)
    #pragma unroll
    for(int j=0;j<4;j++) acc[i][j] = (f32x4){0.f,0.f,0.f,0.f};

  // stage-side addressing (inverse swizzle on global source; LDS dest linear)
  int srl  = tid >> 3;                                    // row within 64-row unit
  int scol = (((tid & 7) * 16) ^ ((srl & 7) << 4)) >> 1;  // source col element
  // read-side addressing
  int rA  = lane & 15;
  int rB0 = (wn & 1) * 64 + rA;
  int cbK0 = (((lane >> 4) * 16)      ^ ((lane & 7) << 4));
  int cbK1 = ((64 + (lane >> 4) * 16) ^ ((lane & 7) << 4));

  // fragment registers: aX = M-half 0, aY = M-half 1; bA = ks0, bB = ks1
  short8 aX0, aX1, aX2, aX3, aY0, aY1, aY2, aY3;
  short8 bA0, bA1, bA2, bA3, bB0, bB1, bB2, bB3;

  int nT = K >> 6;
  // prologue: stage K-tile 0 into dbuf 0 (order: B x4, u_a,u_c, u_b,u_d)
  stageB2(Bt, K, nBase,       0, scol, smem + 65536,         tid, srl);
  stageB2(Bt, K, nBase + 128, 0, scol, smem + 65536 + 16384, tid, srl);
  stageA2(A,  K, mBase,       0, scol, smem,                 tid, srl);
  stageA2(A,  K, mBase + 64,  0, scol, smem + 8192,          tid, srl);
  asm volatile("s_waitcnt vmcnt(2)" ::: "memory");
  __builtin_amdgcn_s_barrier();
  {
    const char* pa0 = smem + wm*16384;
    const char* pb0 = smem + 65536 + (wn>>1)*16384;
    READA(aX, pa0, 0, cbK0);
    READB(bA, pb0, cbK0);
  }

  for(int t = 0; t < nT; ++t){
    int d = t & 1, dn = d ^ 1, k1 = t + 1;
    bool st = (k1 < nT);
    const char* pa  = smem + d*32768 + wm*16384;
    const char* pb  = smem + 65536 + d*32768 + (wn>>1)*16384;
    const char* paN = smem + dn*32768 + wm*16384;
    const char* pbN = smem + 65536 + dn*32768 + (wn>>1)*16384;
    // ---- p0: stage B(v_a',v_b'); confirm u_b,u_d; read aY(ks0); MFMA(aX,bA)
    if(st) stageB2(Bt, K, nBase, k1, scol, smem + 65536 + dn*32768, tid, srl);
    if(st){ asm volatile("s_waitcnt vmcnt(2)" ::: "memory"); }
    else  { asm volatile("s_waitcnt vmcnt(0)" ::: "memory"); }
    __builtin_amdgcn_s_barrier();
    READA(aY, pa, 64, cbK0);
    MFMA16(aX, bA, 0);
    __builtin_amdgcn_s_barrier();
    // ---- p1: stage B(v_c',v_d'); read aX(ks1)+bB(ks1); MFMA(aY,bA)
    if(st) stageB2(Bt, K, nBase + 128, k1, scol, smem + 65536 + dn*32768 + 16384, tid, srl);
    __builtin_amdgcn_s_barrier();
    READA(aX, pa, 0, cbK1);
    READB(bB, pb, cbK1);
    MFMA16(aY, bA, 4);
    __builtin_amdgcn_s_barrier();
    // ---- p2: stage A(u_a',u_c'); read aY(ks1); MFMA(aX,bB)
    if(st) stageA2(A, K, mBase, k1, scol, smem + dn*32768, tid, srl);
    __builtin_amdgcn_s_barrier();
    READA(aY, pa, 64, cbK1);
    MFMA16(aX, bB, 0);
    __builtin_amdgcn_s_barrier();
    // ---- p3: stage A(u_b',u_d'); confirm first 6 of t+1; read aX+bA (t+1); MFMA(aY,bB)
    if(st){ stageA2(A, K, mBase + 64, k1, scol, smem + dn*32768 + 8192, tid, srl);
            asm volatile("s_waitcnt vmcnt(2)" ::: "memory"); }
    __builtin_amdgcn_s_barrier();
    if(st){ READA(aX, paN, 0, cbK0); READB(bA, pbN, cbK0); }
    MFMA16(aY, bB, 4);
    __builtin_amdgcn_s_barrier();
  }

  // direct C-write
  int crow0 = mBase + wm*128 + (lane>>4)*4;
  int ccol0 = nBase + wn*64 + (lane&15);
  #pragma unroll
  for(int i=0;i<8;i++)
    #pragma unroll
    for(int j=0;j<4;j++)
      #pragma unroll
      for(int r=0;r<4;r++){
        float v = acc[i][j][r] * scale;
        size_t off = (size_t)(crow0 + i*16 + r) * N + ccol0 + j*16;
        if(OUT_BF16) Cb[off] = f2bf(v);
        else         Cf[off] = v;
      }

  // mirrored transposed tile for symmetric output (wave-local LDS transpose)
  if(MIRROR && mBase != nBase){
    float* T = (float*)(void*)(smem + wid * 8448);   // 64 x 33 f32 per wave
    int ln15 = lane & 15, lh = lane >> 4;
    #pragma unroll
    for(int c2 = 0; c2 < 4; c2++){
      #pragma unroll
      for(int ii = 0; ii < 2; ii++)
        #pragma unroll
        for(int j = 0; j < 4; j++)
          #pragma unroll
          for(int r = 0; r < 4; r++)
            T[(j*16 + ln15)*33 + ii*16 + lh*4 + r] = acc[c2*2+ii][j][r] * scale;
      asm volatile("s_waitcnt lgkmcnt(0)" ::: "memory");
      __builtin_amdgcn_sched_barrier(0);
      size_t gb = (size_t)(nBase + wn*64 + lane) * N + (mBase + wm*128 + c2*32);
      #pragma unroll
      for(int k4 = 0; k4 < 8; k4++){
        float4 v;
        v.x = T[lane*33 + k4*4 + 0];
        v.y = T[lane*33 + k4*4 + 1];
        v.z = T[lane*33 + k4*4 + 2];
        v.w = T[lane*33 + k4*4 + 3];
        *(float4*)(Cf + gb + k4*4) = v;
      }
      asm volatile("s_waitcnt lgkmcnt(0)" ::: "memory");
      __builtin_amdgcn_sched_barrier(0);
    }
  }
}

// ---------------- m97-style 128x128 NT GEMM (small shapes / split-K) ----------------
template<int OUT_BF16>
__global__ __launch_bounds__(256, 2)
void gemm_bt_kernel(const unsigned short* __restrict__ A,
                    const unsigned short* __restrict__ Bt,
                    float* __restrict__ Cf, unsigned short* __restrict__ Cb,
                    int M, int N, int K, float scale){
  __shared__ __align__(16) char smem[32768];
  unsigned short* sA = (unsigned short*)smem;
  unsigned short* sB = sA + 128 * 64;

  int tid = threadIdx.x, lane = tid & 63, wid = tid >> 6;
  int gx = gridDim.x, gy = gridDim.y;
  int nwg = gx * gy;
  int id = blockIdx.y * gx + blockIdx.x;
  if((nwg & 7) == 0){ int cpx = nwg >> 3; id = (id & 7) * cpx + (id >> 3); }
  int mBase = (id / gx) * 128, nBase = (id % gx) * 128;

  int chRow = lane >> 3;
  int chCol = (lane & 7) * 8;
  int wm = wid >> 1, wn = wid & 1;

  f32x4 acc[4][4];
  #pragma unroll
  for(int i=0;i<4;i++)
    #pragma unroll
    for(int j=0;j<4;j++) acc[i][j] = (f32x4){0.f,0.f,0.f,0.f};

  int kChunk = K / (int)gridDim.z;
  int kStart = kChunk * (int)blockIdx.z;
  if(!OUT_BF16) Cf += (size_t)blockIdx.z * M * N;

  for(int k0 = kStart; k0 < kStart + kChunk; k0 += 64){
    #pragma unroll
    for(int i = 0; i < 4; i++){
      int ch = wid * 4 + i;
      int arow = ch * 8 + chRow;
      gload16(A  + (size_t)(mBase + arow) * K + k0 + chCol, &sA[ch * 512]);
      gload16(Bt + (size_t)(nBase + arow) * K + k0 + chCol, &sB[ch * 512]);
    }
    __syncthreads();
    #pragma unroll
    for(int kk = 0; kk < 64; kk += 32){
      short8 a[4], b[4];
      int krd = kk + (lane >> 4) * 8;
      #pragma unroll
      for(int i = 0; i < 4; i++){
        int row = wm * 64 + i * 16 + (lane & 15);
        a[i] = *reinterpret_cast<const short8*>(&sA[row * 64 + krd]);
        int col = wn * 64 + i * 16 + (lane & 15);
        b[i] = *reinterpret_cast<const short8*>(&sB[col * 64 + krd]);
      }
      #pragma unroll
      for(int i = 0; i < 4; i++)
        #pragma unroll
        for(int j = 0; j < 4; j++)
          acc[i][j] = __builtin_amdgcn_mfma_f32_16x16x32_bf16(a[i], b[j], acc[i][j], 0, 0, 0);
    }
    __syncthreads();
  }

  #pragma unroll
  for(int i = 0; i < 4; i++){
    #pragma unroll
    for(int j = 0; j < 4; j++){
      int row = mBase + wm * 64 + i * 16 + (lane >> 4) * 4;
      int col = nBase + wn * 64 + j * 16 + (lane & 15);
      #pragma unroll
      for(int r = 0; r < 4; r++){
        float v = acc[i][j][r] * scale;
        size_t off = (size_t)(row + r) * N + col;
        if(OUT_BF16) Cb[off] = f2bf(v);
        else         Cf[off] = v;
      }
    }
  }
}

// ---------------- sparsemax: one wave per row of 1024 ----------------
__global__ __launch_bounds__(256)
void sparsemax_kernel(float* __restrict__ S, unsigned short* __restrict__ attnBf){
  int wid = threadIdx.x >> 6, lane = threadIdx.x & 63;
  int row = blockIdx.x * 4 + wid;
  float* z = S + (size_t)row * NHI;
  float v[16];
  #pragma unroll
  for(int j = 0; j < 16; j++) v[j] = z[j * 64 + lane];
  float mx = v[0];
  #pragma unroll
  for(int j = 1; j < 16; j++) mx = fmaxf(mx, v[j]);
  #pragma unroll
  for(int s = 1; s < 64; s <<= 1) mx = fmaxf(mx, __shfl_xor(mx, s, 64));
  float lo = mx - 1.0f, hi = mx;
  for(int it = 0; it < 40; it++){
    float mid = 0.5f * (lo + hi);
    float sum = 0.f;
    #pragma unroll
    for(int j = 0; j < 16; j++) sum += fmaxf(v[j] - mid, 0.f);
    #pragma unroll
    for(int s = 1; s < 64; s <<= 1) sum += __shfl_xor(sum, s, 64);
    if(sum >= 1.0f) lo = mid; else hi = mid;
  }
  float cnt = 0.f, ssum = 0.f;
  #pragma unroll
  for(int j = 0; j < 16; j++){
    if(v[j] > lo){ cnt += 1.f; ssum += v[j]; }
  }
  #pragma unroll
  for(int s = 1; s < 64; s <<= 1){
    cnt  += __shfl_xor(cnt,  s, 64);
    ssum += __shfl_xor(ssum, s, 64);
  }
  float tau = (ssum - 1.0f) / cnt;
  #pragma unroll
  for(int j = 0; j < 16; j++){
    float a = fmaxf(v[j] - tau, 0.f);
    z[j * 64 + lane] = a;
    attnBf[(size_t)row * NHI + j * 64 + lane] = f2bf(a);
  }
}

// ---------------- column sums of attn (f32, [8192,1024]) ----------------
__global__ __launch_bounds__(256)
void colsum_part_kernel(const float* __restrict__ attn, float* __restrict__ part){
  int chunk = blockIdx.x;  // 256 chunks x 32 rows
  int t = threadIdx.x;
  const float* p = attn + (size_t)chunk * 32 * NHI;
  float a0=0,a1=0,a2=0,a3=0;
  for(int r = 0; r < 32; r++){
    a0 += p[(size_t)r*NHI + t];
    a1 += p[(size_t)r*NHI + t + 256];
    a2 += p[(size_t)r*NHI + t + 512];
    a3 += p[(size_t)r*NHI + t + 768];
  }
  float* q = part + (size_t)chunk * NHI;
  q[t]=a0; q[t+256]=a1; q[t+512]=a2; q[t+768]=a3;
}
__global__ __launch_bounds__(256)
void colsum_final_kernel(const float* __restrict__ part, float* __restrict__ colsum){
  int c = blockIdx.x * 256 + threadIdx.x;
  float s = 0.f;
  for(int i = 0; i < 256; i++) s += part[(size_t)i * NHI + c];
  colsum[c] = s;
}

// ---------------- bf16 transpose: in[R,C] -> out[C,R] ----------------
__global__ __launch_bounds__(256)
void transpose_bf16_kernel(const unsigned short* __restrict__ in,
                           unsigned short* __restrict__ out, int R, int C){
  __shared__ unsigned short tile[64][65];
  int c0 = blockIdx.x * 64, r0 = blockIdx.y * 64;
  int t = threadIdx.x;
  int ci = t & 63, r4 = t >> 6;
  #pragma unroll
  for(int k = 0; k < 16; k++){
    int r = k * 4 + r4;
    tile[r][ci] = in[(size_t)(r0 + r) * C + c0 + ci];
  }
  __syncthreads();
  #pragma unroll
  for(int k = 0; k < 16; k++){
    int cc = k * 4 + r4;
    out[(size_t)(c0 + cc) * R + r0 + ci] = tile[ci][cc];
  }
}

// ------ Mt[d,h] = highNT[d,h] + (sum_z aggP_z[d,h]) / (colsum[h]+eps) ------
__global__ __launch_bounds__(256)
void mt_kernel(const unsigned short* __restrict__ highNT, const float* __restrict__ aggP,
               const float* __restrict__ colsum, unsigned short* __restrict__ Mt){
  int idx = blockIdx.x * 256 + threadIdx.x;      // 2048*1024
  int h = idx & 1023;
  float s = aggP[idx] + aggP[idx + 2097152] + aggP[idx + 4194304] + aggP[idx + 6291456];
  float val = bf2f(highNT[idx]) + s / (colsum[h] + 1e-10f);
  Mt[idx] = f2bf(val);
}

extern "C" void kernel_launch(void* const* d_in, const int* in_sizes, int n_in,
                              void* d_out, int out_size, void* d_ws, size_t ws_size,
                              hipStream_t stream){
  const float* low_w  = (const float*)d_in[0];
  const float* high_w = (const float*)d_in[1];
  const float* Wq     = (const float*)d_in[2];
  const float* Wk     = (const float*)d_in[3];
  float* out = (float*)d_out;

  char* ws = (char*)d_ws;
  unsigned short* lowN  = (unsigned short*)(ws);                 // 32 MB; dead after lowNT
  float*          aggP  = (float*)(ws);                          // reuses lowN: 4x8MB partials
  unsigned short* highN = (unsigned short*)(ws + 33554432);      //  4 MB
  unsigned short* WqB   = (unsigned short*)(ws + 37748736);      //  8 MB
  unsigned short* WkB   = (unsigned short*)(ws + 46137344);      //  8 MB
  unsigned short* attnB = (unsigned short*)(ws + 37748736);      // reuse Wq/Wk (16 MB)
  unsigned short* qB    = (unsigned short*)(ws + 54525952);      // 32 MB
  unsigned short* lowNT = qB;                                    // reuse after scores
  unsigned short* kB    = (unsigned short*)(ws + 88080384);      //  4 MB; dead after scores
  float*          part  = (float*)(ws + 88080384);               // reuse kB: 1 MB
  float*          colsum= (float*)(ws + 88080384 + 1048576);     //  4 KB
  unsigned short* attnT = (unsigned short*)(ws + 92274688);      // 16 MB
  unsigned short* Mt    = (unsigned short*)(ws + 109051904);     //  4 MB
  unsigned short* highNT= (unsigned short*)(ws + 113246208);     //  4 MB

  float* out_lowc    = out;               // [8192,2048]
  float* out_lowcos  = out + 16777216;    // [8192,8192]
  float* out_high    = out + 83886080;    // [8192,2048]
  float* out_highcos = out + 100663296;   // [1024,1024]
  float* out_attn    = out + 101711872;   // [8192,1024]

  const float scl = 1.0f / sqrtf((float)DIMV);

  // 1. normalize rows
  rownorm_kernel<1><<<NL,  256, 0, stream>>>(low_w,  out_lowc, lowN);
  rownorm_kernel<0><<<NHI, 256, 0, stream>>>(high_w, nullptr,  highN);
  // 2. cast weights
  cast_bf16_kernel<<<2048, 256, 0, stream>>>(Wq, WqB);
  cast_bf16_kernel<<<2048, 256, 0, stream>>>(Wk, WkB);
  // 3. low_cos = lowN lowN^T [8192,8192], symmetric upper triangle + mirror (8-phase)
  gemm256_kernel<0,1><<<528, 512, 0, stream>>>(lowN, lowN, out_lowcos, nullptr,
                                               NL, NL, DIMV, 1.0f);
  // 4. high_cos = highN highN^T [1024,1024] (m97 kernel)
  gemm_bt_kernel<0><<<dim3(8,8), 256, 0, stream>>>(highN, highN, out_highcos, nullptr,
                                                   NHI, NHI, DIMV, 1.0f);
  // 5. q = lowN Wq^T (bf16, 8-phase)   k = highN Wk^T (bf16, m97)
  gemm256_kernel<1,0><<<dim3(8,32), 512, 0, stream>>>(lowN, WqB, nullptr, qB,
                                                      NL, DIMV, DIMV, 1.0f);
  gemm_bt_kernel<1><<<dim3(16,8), 256, 0, stream>>>(highN, WkB, nullptr, kB,
                                                    NHI, DIMV, DIMV, 1.0f);
  // 6. scores = scale * q k^T -> f32 (8-phase)
  gemm256_kernel<0,0><<<dim3(4,32), 512, 0, stream>>>(qB, kB, out_attn, nullptr,
                                                      NL, NHI, DIMV, scl);
  // 7. sparsemax rows in-place (+ bf16 copy into reused Wq/Wk space)
  sparsemax_kernel<<<NL/4, 256, 0, stream>>>(out_attn, attnB);
  // 8. column sums of attn (part reuses dead kB)
  colsum_part_kernel<<<256, 256, 0, stream>>>(out_attn, part);
  colsum_final_kernel<<<4, 256, 0, stream>>>(part, colsum);
  // 9. transposes: attnT [1024,8192], lowNT [2048,8192], highNT [2048,1024]
  transpose_bf16_kernel<<<dim3(NHI/64, NL/64), 256, 0, stream>>>(attnB, attnT, NL, NHI);
  transpose_bf16_kernel<<<dim3(DIMV/64, NL/64), 256, 0, stream>>>(lowN, lowNT, NL, DIMV);
  transpose_bf16_kernel<<<dim3(DIMV/64, NHI/64), 256, 0, stream>>>(highN, highNT, NHI, DIMV);
  // 10. aggP_z[d,h] = sum_{k in chunk z} lowN[k,d] attn[k,h]  (m97 split-K x4)
  gemm_bt_kernel<0><<<dim3(8,16,4), 256, 0, stream>>>(lowNT, attnT, aggP, nullptr,
                                                      DIMV, NHI, NL, 1.0f);
  // 11. Mt = highN^T + sum(aggP) / colsum  (bf16, [2048,1024])
  mt_kernel<<<8192, 256, 0, stream>>>(highNT, aggP, colsum, Mt);
  // 12. output_high = attn (highN + agg) = attn Mt^T  [8192,2048] (8-phase)
  gemm256_kernel<0,0><<<dim3(8,32), 512, 0, stream>>>(attnB, Mt, out_high, nullptr,
                                                      NL, DIMV, NHI, 1.0f);
}

// Round 6
// 642.046 us; speedup vs baseline: 1.1373x; 1.1166x over previous
//
#include <hip/hip_runtime.h>
#include <hip/hip_bf16.h>
#include <stdint.h>

#define NL   8192
#define NHI  1024
#define DIMV 2048

typedef __attribute__((ext_vector_type(8))) short short8;
typedef __attribute__((ext_vector_type(4))) float f32x4;

__device__ __forceinline__ unsigned short f2bf(float x){
  unsigned u = __float_as_uint(x);
  u += 0x7FFFu + ((u >> 16) & 1u);
  return (unsigned short)(u >> 16);
}
__device__ __forceinline__ float bf2f(unsigned short b){
  return __uint_as_float(((unsigned)b) << 16);
}
__device__ __forceinline__ unsigned pack2bf(float a, float b){
  return (unsigned)f2bf(a) | ((unsigned)f2bf(b) << 16);
}

__device__ __forceinline__ void gload16(const void* g, void* l){
  __builtin_amdgcn_global_load_lds(
      (const __attribute__((address_space(1))) unsigned int*)g,
      (__attribute__((address_space(3))) unsigned int*)l, 16, 0, 0);
}

// ---------------- row-normalize (and emit bf16 copy) ----------------
template<int WRITE_F32>
__global__ __launch_bounds__(256)
void rownorm_kernel(const float* __restrict__ W, float* __restrict__ outF32,
                    unsigned short* __restrict__ outBf){
  int row = blockIdx.x;
  const float* r = W + (size_t)row * DIMV;
  int base = threadIdx.x * 8;
  float4 x0 = *(const float4*)(r + base);
  float4 x1 = *(const float4*)(r + base + 4);
  float ss = x0.x*x0.x + x0.y*x0.y + x0.z*x0.z + x0.w*x0.w
           + x1.x*x1.x + x1.y*x1.y + x1.z*x1.z + x1.w*x1.w;
  #pragma unroll
  for(int s = 1; s < 64; s <<= 1) ss += __shfl_xor(ss, s, 64);
  __shared__ float red[4];
  if((threadIdx.x & 63) == 0) red[threadIdx.x >> 6] = ss;
  __syncthreads();
  float tot = red[0] + red[1] + red[2] + red[3];
  float inv = 1.0f / sqrtf(tot);
  float y0=x0.x*inv, y1=x0.y*inv, y2=x0.z*inv, y3=x0.w*inv;
  float y4=x1.x*inv, y5=x1.y*inv, y6=x1.z*inv, y7=x1.w*inv;
  if(WRITE_F32){
    float* o = outF32 + (size_t)row * DIMV + base;
    *(float4*)o       = make_float4(y0,y1,y2,y3);
    *(float4*)(o + 4) = make_float4(y4,y5,y6,y7);
  }
  uint4 u;
  u.x = pack2bf(y0,y1); u.y = pack2bf(y2,y3);
  u.z = pack2bf(y4,y5); u.w = pack2bf(y6,y7);
  *(uint4*)(outBf + (size_t)row * DIMV + base) = u;
}

// ---------------- fused f32 -> bf16 cast of Wq and Wk ----------------
__global__ __launch_bounds__(256)
void cast2_kernel(const float* __restrict__ a, const float* __restrict__ b,
                  unsigned short* __restrict__ oa, unsigned short* __restrict__ ob){
  int id = blockIdx.x;
  const float* in; unsigned short* out;
  if(id < 2048){ in = a; out = oa; } else { in = b; out = ob; id -= 2048; }
  size_t i = ((size_t)id * 256 + threadIdx.x) * 8;
  float4 x0 = *(const float4*)(in + i);
  float4 x1 = *(const float4*)(in + i + 4);
  uint4 u;
  u.x = pack2bf(x0.x,x0.y); u.y = pack2bf(x0.z,x0.w);
  u.z = pack2bf(x1.x,x1.y); u.w = pack2bf(x1.z,x1.w);
  *(uint4*)(out + i) = u;
}

// ---------------- NT GEMM: C[M,N] = scale * A[M,K] x Bt[N,K]^T ----------------
// 128x128 tile, BK=64, 256 threads (4 waves 2x2), mfma_f32_16x16x32_bf16.
// MIRROR=1: symmetric C (A==Bt, M==N); 1D grid over upper triangle, each
//           off-diagonal block also writes the transposed tile (LDS-staged).
// split-K via gridDim.z (f32 output only): partial z written to Cf + z*M*N.
template<int OUT_BF16, int MIRROR>
__global__ __launch_bounds__(256, 2)
void gemm_bt_kernel(const unsigned short* __restrict__ A,
                    const unsigned short* __restrict__ Bt,
                    float* __restrict__ Cf, unsigned short* __restrict__ Cb,
                    int M, int N, int K, float scale){
  __shared__ __align__(16) char smem[32768];
  unsigned short* sA = (unsigned short*)smem;
  unsigned short* sB = sA + 128 * 64;

  int tid = threadIdx.x, lane = tid & 63, wid = tid >> 6;
  int mBase, nBase;
  if(MIRROR){
    int nwg = gridDim.x;                       // 2080, divisible by 8
    int id = blockIdx.x;
    int cpx = nwg >> 3;
    id = (id & 7) * cpx + (id >> 3);           // XCD-contiguous chunks
    int bi = 0;
    while(((bi+1)*64 - (((bi+1)*bi) >> 1)) <= id) bi++;
    int off = bi*64 - ((bi*(bi-1)) >> 1);
    int bj = bi + (id - off);
    mBase = bi * 128; nBase = bj * 128;
  } else {
    int gx = gridDim.x, gy = gridDim.y;
    int nwg = gx * gy;
    int id = blockIdx.y * gx + blockIdx.x;
    if((nwg & 7) == 0){ int cpx = nwg >> 3; id = (id & 7) * cpx + (id >> 3); }
    mBase = (id / gx) * 128; nBase = (id % gx) * 128;
  }

  int chRow = lane >> 3;          // row within 8-row chunk
  int chCol = (lane & 7) * 8;     // 16B-granule column
  int wm = wid >> 1, wn = wid & 1;

  f32x4 acc[4][4];
  #pragma unroll
  for(int i=0;i<4;i++)
    #pragma unroll
    for(int j=0;j<4;j++) acc[i][j] = (f32x4){0.f,0.f,0.f,0.f};

  int kChunk = K / (int)gridDim.z;
  int kStart = kChunk * (int)blockIdx.z;
  if(!OUT_BF16) Cf += (size_t)blockIdx.z * M * N;

  for(int k0 = kStart; k0 < kStart + kChunk; k0 += 64){
    #pragma unroll
    for(int i = 0; i < 4; i++){
      int ch = wid * 4 + i;                  // 0..15 chunk of 8 rows
      int arow = ch * 8 + chRow;             // 0..127
      gload16(A  + (size_t)(mBase + arow) * K + k0 + chCol, &sA[ch * 512]);
      gload16(Bt + (size_t)(nBase + arow) * K + k0 + chCol, &sB[ch * 512]);
    }
    __syncthreads();
    #pragma unroll
    for(int kk = 0; kk < 64; kk += 32){
      short8 a[4], b[4];
      int krd = kk + (lane >> 4) * 8;
      #pragma unroll
      for(int i = 0; i < 4; i++){
        int row = wm * 64 + i * 16 + (lane & 15);
        a[i] = *reinterpret_cast<const short8*>(&sA[row * 64 + krd]);
        int col = wn * 64 + i * 16 + (lane & 15);
        b[i] = *reinterpret_cast<const short8*>(&sB[col * 64 + krd]);
      }
      #pragma unroll
      for(int i = 0; i < 4; i++)
        #pragma unroll
        for(int j = 0; j < 4; j++)
          acc[i][j] = __builtin_amdgcn_mfma_f32_16x16x32_bf16(a[i], b[j], acc[i][j], 0, 0, 0);
    }
    __syncthreads();
  }

  // normal C-write
  #pragma unroll
  for(int i = 0; i < 4; i++){
    #pragma unroll
    for(int j = 0; j < 4; j++){
      int row = mBase + wm * 64 + i * 16 + (lane >> 4) * 4;
      int col = nBase + wn * 64 + j * 16 + (lane & 15);
      #pragma unroll
      for(int r = 0; r < 4; r++){
        float v = acc[i][j][r] * scale;
        size_t off = (size_t)(row + r) * N + col;
        if(OUT_BF16) Cb[off] = f2bf(v);
        else         Cf[off] = v;
      }
    }
  }

  // mirrored tile write for symmetric output (off-diagonal blocks only)
  if(MIRROR && mBase != nBase){
    float* tf = (float*)smem;                 // 64 x 65 f32 = 16.6 KB
    #pragma unroll
    for(int rq = 0; rq < 4; rq++){
      int qm = rq >> 1, qn = rq & 1;
      __syncthreads();                        // smem free / prev round read
      if(wm == qm && wn == qn){
        #pragma unroll
        for(int i = 0; i < 4; i++)
          #pragma unroll
          for(int j = 0; j < 4; j++){
            int rl = i * 16 + (lane >> 4) * 4;
            int cl = j * 16 + (lane & 15);
            #pragma unroll
            for(int r = 0; r < 4; r++)
              tf[(rl + r) * 65 + cl] = acc[i][j][r] * scale;
          }
      }
      __syncthreads();
      // cooperative coalesced write of the transposed 64x64 quadrant
      int mr = tid >> 2, seg = tid & 3;
      size_t obase = (size_t)(nBase + qn * 64 + mr) * N + mBase + qm * 64 + seg * 16;
      #pragma unroll
      for(int k4 = 0; k4 < 4; k4++){
        float4 v;
        v.x = tf[(seg * 16 + k4 * 4 + 0) * 65 + mr];
        v.y = tf[(seg * 16 + k4 * 4 + 1) * 65 + mr];
        v.z = tf[(seg * 16 + k4 * 4 + 2) * 65 + mr];
        v.w = tf[(seg * 16 + k4 * 4 + 3) * 65 + mr];
        *(float4*)(Cf + obase + k4 * 4) = v;
      }
    }
  }
}

// ---------------- split-K combiners ----------------
__global__ __launch_bounds__(256)
void combine_bf16_kernel(const float* __restrict__ p, unsigned short* __restrict__ out,
                         size_t stride){
  size_t i = ((size_t)blockIdx.x * 256 + threadIdx.x) * 8;
  float4 a0 = *(const float4*)(p + i);
  float4 a1 = *(const float4*)(p + i + 4);
  float4 b0 = *(const float4*)(p + stride + i);
  float4 b1 = *(const float4*)(p + stride + i + 4);
  uint4 u;
  u.x = pack2bf(a0.x+b0.x, a0.y+b0.y); u.y = pack2bf(a0.z+b0.z, a0.w+b0.w);
  u.z = pack2bf(a1.x+b1.x, a1.y+b1.y); u.w = pack2bf(a1.z+b1.z, a1.w+b1.w);
  *(uint4*)(out + i) = u;
}
__global__ __launch_bounds__(256)
void combine_f32_kernel(const float* __restrict__ p, float* __restrict__ out,
                        size_t stride){
  size_t i = ((size_t)blockIdx.x * 256 + threadIdx.x) * 8;
  float4 a0 = *(const float4*)(p + i);
  float4 a1 = *(const float4*)(p + i + 4);
  float4 b0 = *(const float4*)(p + stride + i);
  float4 b1 = *(const float4*)(p + stride + i + 4);
  *(float4*)(out + i)     = make_float4(a0.x+b0.x, a0.y+b0.y, a0.z+b0.z, a0.w+b0.w);
  *(float4*)(out + i + 4) = make_float4(a1.x+b1.x, a1.y+b1.y, a1.z+b1.z, a1.w+b1.w);
}

// ---------------- sparsemax: one wave per row of 1024 ----------------
__global__ __launch_bounds__(256)
void sparsemax_kernel(float* __restrict__ S, unsigned short* __restrict__ attnBf){
  int wid = threadIdx.x >> 6, lane = threadIdx.x & 63;
  int row = blockIdx.x * 4 + wid;
  float* z = S + (size_t)row * NHI;
  float v[16];
  #pragma unroll
  for(int j = 0; j < 16; j++) v[j] = z[j * 64 + lane];
  float mx = v[0];
  #pragma unroll
  for(int j = 1; j < 16; j++) mx = fmaxf(mx, v[j]);
  #pragma unroll
  for(int s = 1; s < 64; s <<= 1) mx = fmaxf(mx, __shfl_xor(mx, s, 64));
  float lo = mx - 1.0f, hi = mx;
  for(int it = 0; it < 40; it++){
    float mid = 0.5f * (lo + hi);
    float sum = 0.f;
    #pragma unroll
    for(int j = 0; j < 16; j++) sum += fmaxf(v[j] - mid, 0.f);
    #pragma unroll
    for(int s = 1; s < 64; s <<= 1) sum += __shfl_xor(sum, s, 64);
    if(sum >= 1.0f) lo = mid; else hi = mid;
  }
  float cnt = 0.f, ssum = 0.f;
  #pragma unroll
  for(int j = 0; j < 16; j++){
    if(v[j] > lo){ cnt += 1.f; ssum += v[j]; }
  }
  #pragma unroll
  for(int s = 1; s < 64; s <<= 1){
    cnt  += __shfl_xor(cnt,  s, 64);
    ssum += __shfl_xor(ssum, s, 64);
  }
  float tau = (ssum - 1.0f) / cnt;
  #pragma unroll
  for(int j = 0; j < 16; j++){
    float a = fmaxf(v[j] - tau, 0.f);
    z[j * 64 + lane] = a;
    attnBf[(size_t)row * NHI + j * 64 + lane] = f2bf(a);
  }
}

// ---------------- column sums of attn (f32, [8192,1024]) ----------------
__global__ __launch_bounds__(256)
void colsum_part_kernel(const float* __restrict__ attn, float* __restrict__ part){
  int chunk = blockIdx.x;  // 256 chunks x 32 rows
  int t = threadIdx.x;
  const float* p = attn + (size_t)chunk * 32 * NHI;
  float a0=0,a1=0,a2=0,a3=0;
  for(int r = 0; r < 32; r++){
    a0 += p[(size_t)r*NHI + t];
    a1 += p[(size_t)r*NHI + t + 256];
    a2 += p[(size_t)r*NHI + t + 512];
    a3 += p[(size_t)r*NHI + t + 768];
  }
  float* q = part + (size_t)chunk * NHI;
  q[t]=a0; q[t+256]=a1; q[t+512]=a2; q[t+768]=a3;
}
__global__ __launch_bounds__(256)
void colsum_final_kernel(const float* __restrict__ part, float* __restrict__ colsum){
  int c = blockIdx.x * 256 + threadIdx.x;
  float s = 0.f;
  for(int i = 0; i < 256; i++) s += part[(size_t)i * NHI + c];
  colsum[c] = s;
}

// ---- fused bf16 transposes: attnB->attnT, lowN->lowNT, highN->highNT ----
__global__ __launch_bounds__(256)
void transpose3_kernel(const unsigned short* __restrict__ attnB, unsigned short* __restrict__ attnT,
                       const unsigned short* __restrict__ lowN,  unsigned short* __restrict__ lowNT,
                       const unsigned short* __restrict__ highN, unsigned short* __restrict__ highNT){
  __shared__ unsigned short tile[64][65];
  int id = blockIdx.x;
  const unsigned short* in; unsigned short* out; int R, C, tx, ty;
  if(id < 2048){        in = attnB; out = attnT;  R = NL;  C = NHI;  tx = id & 15; ty = id >> 4; }
  else if(id < 6144){ id -= 2048;
                        in = lowN;  out = lowNT;  R = NL;  C = DIMV; tx = id & 31; ty = id >> 5; }
  else {              id -= 6144;
                        in = highN; out = highNT; R = NHI; C = DIMV; tx = id & 31; ty = id >> 5; }
  int c0 = tx * 64, r0 = ty * 64;
  int t = threadIdx.x;
  int ci = t & 63, r4 = t >> 6;
  #pragma unroll
  for(int k = 0; k < 16; k++){
    int r = k * 4 + r4;
    tile[r][ci] = in[(size_t)(r0 + r) * C + c0 + ci];
  }
  __syncthreads();
  #pragma unroll
  for(int k = 0; k < 16; k++){
    int cc = k * 4 + r4;
    out[(size_t)(c0 + cc) * R + r0 + ci] = tile[ci][cc];
  }
}

// ------ Mt[d,h] = highNT[d,h] + (sum_z aggP_z[d,h]) / (colsum[h]+eps) ------
__global__ __launch_bounds__(256)
void mt_kernel(const unsigned short* __restrict__ highNT, const float* __restrict__ aggP,
               const float* __restrict__ colsum, unsigned short* __restrict__ Mt){
  int idx = blockIdx.x * 256 + threadIdx.x;      // 2048*1024
  int h = idx & 1023;
  float s = aggP[idx] + aggP[idx + 2097152] + aggP[idx + 4194304] + aggP[idx + 6291456];
  float val = bf2f(highNT[idx]) + s / (colsum[h] + 1e-10f);
  Mt[idx] = f2bf(val);
}

extern "C" void kernel_launch(void* const* d_in, const int* in_sizes, int n_in,
                              void* d_out, int out_size, void* d_ws, size_t ws_size,
                              hipStream_t stream){
  const float* low_w  = (const float*)d_in[0];
  const float* high_w = (const float*)d_in[1];
  const float* Wq     = (const float*)d_in[2];
  const float* Wk     = (const float*)d_in[3];
  float* out = (float*)d_out;

  char* ws = (char*)d_ws;
  unsigned short* lowN  = (unsigned short*)(ws);                 // 32 MB; dead after transpose3
  float*          aggP  = (float*)(ws);                          // reuses lowN: 4x8MB partials
  unsigned short* highN = (unsigned short*)(ws + 33554432);      //  4 MB
  unsigned short* WqB   = (unsigned short*)(ws + 37748736);      //  8 MB
  unsigned short* WkB   = (unsigned short*)(ws + 46137344);      //  8 MB
  unsigned short* attnB = (unsigned short*)(ws + 37748736);      // reuse Wq/Wk (16 MB)
  unsigned short* qB    = (unsigned short*)(ws + 54525952);      // 32 MB
  unsigned short* lowNT = qB;                                    // reuse after scores
  unsigned short* kB    = (unsigned short*)(ws + 88080384);      //  4 MB; dead after scores
  float*          part  = (float*)(ws + 88080384);               // reuse kB: 1 MB
  float*          colsum= (float*)(ws + 88080384 + 1048576);     //  4 KB
  unsigned short* attnT = (unsigned short*)(ws + 92274688);      // 16 MB (from step 9)
  float*          kPart = (float*)(ws + 92274688);               // 16 MB (step 5, pre-attnT)
  unsigned short* Mt    = (unsigned short*)(ws + 109051904);     //  4 MB (from step 11)
  unsigned short* highNT= (unsigned short*)(ws + 113246208);     //  4 MB (from step 9)
  float*          hcPart= (float*)(ws + 109051904);              //  8 MB (step 4, pre-Mt/highNT)

  float* out_lowc    = out;               // [8192,2048]
  float* out_lowcos  = out + 16777216;    // [8192,8192]
  float* out_high    = out + 83886080;    // [8192,2048]
  float* out_highcos = out + 100663296;   // [1024,1024]
  float* out_attn    = out + 101711872;   // [8192,1024]

  const float scl = 1.0f / sqrtf((float)DIMV);

  // 1. normalize rows
  rownorm_kernel<1><<<NL,  256, 0, stream>>>(low_w,  out_lowc, lowN);
  rownorm_kernel<0><<<NHI, 256, 0, stream>>>(high_w, nullptr,  highN);
  // 2. cast both weights (fused)
  cast2_kernel<<<4096, 256, 0, stream>>>(Wq, Wk, WqB, WkB);
  // 3. low_cos = lowN lowN^T [8192,8192], symmetric: upper triangle + mirror
  gemm_bt_kernel<0,1><<<2080, 256, 0, stream>>>(lowN, lowN, out_lowcos, nullptr,
                                                NL, NL, DIMV, 1.0f);
  // 4. high_cos = highN highN^T [1024,1024], split-K x2 -> combine
  gemm_bt_kernel<0,0><<<dim3(8,8,2), 256, 0, stream>>>(highN, highN, hcPart, nullptr,
                                                       NHI, NHI, DIMV, 1.0f);
  combine_f32_kernel<<<512, 256, 0, stream>>>(hcPart, out_highcos, 1048576);
  // 5. q = lowN Wq^T (bf16)   k = highN Wk^T (split-K x2 f32 -> bf16 combine)
  gemm_bt_kernel<1,0><<<dim3(16,64), 256, 0, stream>>>(lowN, WqB, nullptr, qB,
                                                       NL, DIMV, DIMV, 1.0f);
  gemm_bt_kernel<0,0><<<dim3(16,8,2), 256, 0, stream>>>(highN, WkB, kPart, nullptr,
                                                        NHI, DIMV, DIMV, 1.0f);
  combine_bf16_kernel<<<1024, 256, 0, stream>>>(kPart, kB, 2097152);
  // 6. scores = scale * q k^T -> f32 into attn output slot
  gemm_bt_kernel<0,0><<<dim3(8,64), 256, 0, stream>>>(qB, kB, out_attn, nullptr,
                                                      NL, NHI, DIMV, scl);
  // 7. sparsemax rows in-place (+ bf16 copy into reused Wq/Wk space)
  sparsemax_kernel<<<NL/4, 256, 0, stream>>>(out_attn, attnB);
  // 8. column sums of attn (part reuses dead kB)
  colsum_part_kernel<<<256, 256, 0, stream>>>(out_attn, part);
  colsum_final_kernel<<<4, 256, 0, stream>>>(part, colsum);
  // 9. fused transposes: attnT [1024,8192], lowNT [2048,8192], highNT [2048,1024]
  transpose3_kernel<<<6656, 256, 0, stream>>>(attnB, attnT, lowN, lowNT, highN, highNT);
  // 10. aggP_z[d,h] = sum_{k in chunk z} lowN[k,d] attn[k,h]  (split-K x4, overwrites lowN)
  gemm_bt_kernel<0,0><<<dim3(8,16,4), 256, 0, stream>>>(lowNT, attnT, aggP, nullptr,
                                                        DIMV, NHI, NL, 1.0f);
  // 11. Mt = highN^T + sum(aggP) / colsum  (bf16, [2048,1024])
  mt_kernel<<<8192, 256, 0, stream>>>(highNT, aggP, colsum, Mt);
  // 12. output_high = attn (highN + agg) = attn Mt^T  [8192,2048]
  gemm_bt_kernel<0,0><<<dim3(16,64), 256, 0, stream>>>(attnB, Mt, out_high, nullptr,
                                                       NL, DIMV, NHI, 1.0f);
}